// Round 6
// baseline (43.513 us; speedup 1.0000x reference)
//
#include <hip/hip_runtime.h>
#include <hip/hip_cooperative_groups.h>

namespace cg = cooperative_groups;

#define NB 32
#define NA 3
#define NT 30
#define NCLS 80
#define NPT 2880            // 3 * NB * NT slots, one wave each
#define NBLK 180            // 16 waves (slots) per 1024-thread block; blocks scale-pure (60/scale)

struct __align__(32) BP { double sq, bce, cnt, pad; };

// Single cooperative kernel: per-wave target prep (keys + last-wins dedup +
// class union), cell gather + loss terms, block partial (plain store),
// grid-wide sync, then block 0 reduces 180 partials and writes the loss.
__global__ __launch_bounds__(1024) void yolo_coop(
    const float* __restrict__ o0, const float* __restrict__ o1, const float* __restrict__ o2,
    const float* __restrict__ a0, const float* __restrict__ a1, const float* __restrict__ a2,
    const float* __restrict__ tg, BP* __restrict__ parts, float* __restrict__ dout)
{
    const int wid  = threadIdx.x >> 6;
    const int lane = threadIdx.x & 63;
    const int slot = blockIdx.x * 16 + wid;      // 0..2879 (180*16 = 2880, never OOB)
    const int sb = slot / NT, t = slot % NT;
    const int s = sb / NB, b = sb % NB;
    const int g = 13 << s;
    const float gf = (float)g;

    const float* ap = (s == 0) ? a0 : (s == 1) ? a1 : a2;
    const float aw0 = ap[0], ah0 = ap[1], aw1 = ap[2], ah1 = ap[3], aw2 = ap[4], ah2 = ap[5];

    // ---- prep: lane i computes cell key for target i of batch b ----
    int key = -1, cls = 0;
    float gx = 0.f, gy = 0.f, gw = 1.f, gh = 1.f;
    if (lane < NT) {
        const float* tp = tg + (size_t)(b * NT + lane) * 5;
        float x0 = tp[0], y0 = tp[1], x1 = tp[2], y1 = tp[3];
        cls = (int)tp[4];
        gx = x0 * gf; gy = y0 * gf;
        gw = fabsf(x1 - x0) * (416.0f * gf);
        gh = fabsf(y1 - y0) * (416.0f * gf);
        int best = 0; float bi = -1.0f;
        { float in0 = fminf(aw0, gw) * fminf(ah0, gh); float u = 1e-8f + aw0 * ah0 + gw * gh - in0; float io = in0 / u; if (io > bi) { bi = io; best = 0; } }
        { float in1 = fminf(aw1, gw) * fminf(ah1, gh); float u = 1e-8f + aw1 * ah1 + gw * gh - in1; float io = in1 / u; if (io > bi) { bi = io; best = 1; } }
        { float in2 = fminf(aw2, gw) * fminf(ah2, gh); float u = 1e-8f + aw2 * ah2 + gw * gh - in2; float io = in2 / u; if (io > bi) { bi = io; best = 2; } }
        key = ((b * NA + best) * g + (int)gx) * g + (int)gy;
    }

    // ---- dedup: last target with same key wins; class union over all matches ----
    const int key_t = __shfl(key, t);
    const unsigned long long m = __ballot(lane < NT && key == key_t);
    const bool win = (m >> (t + 1)) == 0ull;                    // no later target hits this cell
    const unsigned long long mle = m & ((2ull << t) - 1ull);    // matches with index <= t

    unsigned long long lo = 0ull, hi = 0ull;
    if ((mle >> lane) & 1ull) {
        if (cls < 64) lo = 1ull << cls; else hi = 1ull << (cls - 64);
    }
    for (int off = 1; off < 64; off <<= 1) {
        lo |= __shfl_xor(lo, off);
        hi |= __shfl_xor(hi, off);
    }

    // ---- regression targets for slot t (broadcast from lane t) ----
    const float gxt = __shfl(gx, t), gyt = __shfl(gy, t);
    const float gwt = __shfl(gw, t), ght = __shfl(gh, t);
    const int bestt = (key_t / (g * g)) % NA;
    const float awb = (bestt == 0) ? aw0 : (bestt == 1) ? aw1 : aw2;
    const float ahb = (bestt == 0) ? ah0 : (bestt == 1) ? ah1 : ah2;
    const float txv = gxt - floorf(gxt);
    const float tyv = gyt - floorf(gyt);
    const float twv = logf(gwt / awb);
    const float thv = logf(ght / ahb);

    // ---- gather the 85-float cell, accumulate loss terms ----
    double vsq = 0.0, vbce = 0.0;
    if (win) {
        const float* op = (s == 0) ? o0 : (s == 1) ? o1 : o2;
        const float* cell = op + (size_t)key_t * (5 + NCLS);
        {
            float x = cell[lane];                                // elements 0..63
            if (lane < 4) {
                float tv = (lane == 0) ? txv : (lane == 1) ? tyv : (lane == 2) ? twv : thv;
                float d = x - tv;
                vsq = (double)d * d;
            } else if (lane >= 5) {
                int c = lane - 5;                                // classes 0..58
                bool one = (lo >> c) & 1ull;
                float p = fminf(fmaxf(x, 1e-7f), 1.0f - 1e-7f);
                vbce = (double)(one ? -logf(p) : -logf(1.0f - p));
            }
        }
        if (lane < 21) {
            float x = cell[64 + lane];                           // classes 59..79
            int c = 59 + lane;
            bool one = (c < 64) ? ((lo >> c) & 1ull) : ((hi >> (c - 64)) & 1ull);
            float p = fminf(fmaxf(x, 1e-7f), 1.0f - 1e-7f);
            vbce += (double)(one ? -logf(p) : -logf(1.0f - p));
        }
    }
    for (int off = 32; off > 0; off >>= 1) {
        vsq  += __shfl_down(vsq, off);
        vbce += __shfl_down(vbce, off);
    }

    // ---- block partial: 16 waves -> LDS -> one plain store ----
    __shared__ double ssq[16], sbce[16];
    __shared__ int    scnt[16];
    if (lane == 0) { ssq[wid] = vsq; sbce[wid] = vbce; scnt[wid] = win ? 1 : 0; }
    __syncthreads();
    if (threadIdx.x == 0) {
        double psq = 0.0, pbce = 0.0; int pcnt = 0;
        for (int w = 0; w < 16; ++w) { psq += ssq[w]; pbce += sbce[w]; pcnt += scnt[w]; }
        BP p; p.sq = psq; p.bce = pbce; p.cnt = (double)pcnt; p.pad = 0.0;
        parts[blockIdx.x] = p;
    }

    // ---- grid-wide barrier (runtime-managed, no persistent state) ----
    cg::this_grid().sync();

    // ---- block 0: deterministic final reduction over 180 partials ----
    if (blockIdx.x == 0) {
        double vs[3] = {0, 0, 0}, vb[3] = {0, 0, 0}, vc[3] = {0, 0, 0};
        const int i = threadIdx.x;
        if (i < NBLK) {                      // blocks scale-pure: 60 per scale
            BP p = parts[i];
            int sc = i / (NBLK / 3);
            vs[sc] = p.sq; vb[sc] = p.bce; vc[sc] = p.cnt;
        }
        for (int off = 32; off > 0; off >>= 1)
            for (int sc = 0; sc < 3; ++sc) {
                vs[sc] += __shfl_down(vs[sc], off);
                vb[sc] += __shfl_down(vb[sc], off);
                vc[sc] += __shfl_down(vc[sc], off);
            }
        __shared__ double rs[16][3], rb[16][3], rc[16][3];
        if (lane == 0)
            for (int sc = 0; sc < 3; ++sc) { rs[wid][sc] = vs[sc]; rb[wid][sc] = vb[sc]; rc[wid][sc] = vc[sc]; }
        __syncthreads();
        if (threadIdx.x == 0) {
            double loss = 0.0;
            for (int sc = 0; sc < 3; ++sc) {
                double sq = 0.0, bce = 0.0, cn = 0.0;
                for (int w = 0; w < 16; ++w) { sq += rs[w][sc]; bce += rb[w][sc]; cn += rc[w][sc]; }
                double c = (cn > 0.0) ? cn : 1.0;
                loss += sq / c + bce / (c * (double)NCLS);
            }
            dout[0] = (float)loss;
        }
    }
}

extern "C" void kernel_launch(void* const* d_in, const int* in_sizes, int n_in,
                              void* d_out, int out_size, void* d_ws, size_t ws_size,
                              hipStream_t stream) {
    const float* o0 = (const float*)d_in[0];
    const float* o1 = (const float*)d_in[1];
    const float* o2 = (const float*)d_in[2];
    const float* a0 = (const float*)d_in[3];
    const float* a1 = (const float*)d_in[4];
    const float* a2 = (const float*)d_in[5];
    const float* tg = (const float*)d_in[6];
    float* out = (float*)d_out;

    BP* parts = (BP*)d_ws;      // 180 * 32 B = 5,760 B

    void* args[] = { (void*)&o0, (void*)&o1, (void*)&o2,
                     (void*)&a0, (void*)&a1, (void*)&a2,
                     (void*)&tg, (void*)&parts, (void*)&out };
    hipLaunchCooperativeKernel((const void*)yolo_coop, dim3(NBLK), dim3(1024),
                               args, 0, stream);
}

// Round 7
// 13.034 us; speedup vs baseline: 3.3383x; 3.3383x over previous
//
#include <hip/hip_runtime.h>

#define NB 32
#define NA 3
#define NT 30
#define NCLS 80
#define NPT 2880            // 3 * NB * NT slots, one wave each
#define NBLK 180            // 16 waves (slots) per 1024-thread block; scale-pure (60/scale)

struct __align__(32) BP { double sq, bce, cnt, pad; };

// Fused prep + accumulate: per-wave target prep (keys + last-wins dedup +
// class union), cell gather + loss terms, one plain-store partial per block.
__global__ __launch_bounds__(1024) void yolo_fused(
    const float* __restrict__ o0, const float* __restrict__ o1, const float* __restrict__ o2,
    const float* __restrict__ a0, const float* __restrict__ a1, const float* __restrict__ a2,
    const float* __restrict__ tg, BP* __restrict__ parts)
{
    const int wid  = threadIdx.x >> 6;
    const int lane = threadIdx.x & 63;
    const int slot = blockIdx.x * 16 + wid;      // 0..2879 (180*16 = 2880, never OOB)
    const int sb = slot / NT, t = slot % NT;
    const int s = sb / NB, b = sb % NB;
    const int g = 13 << s;
    const float gf = (float)g;

    const float* ap = (s == 0) ? a0 : (s == 1) ? a1 : a2;
    const float aw0 = ap[0], ah0 = ap[1], aw1 = ap[2], ah1 = ap[3], aw2 = ap[4], ah2 = ap[5];

    // ---- prep: lane i computes cell key for target i of batch b ----
    int key = -1, cls = 0;
    float gx = 0.f, gy = 0.f, gw = 1.f, gh = 1.f;
    if (lane < NT) {
        const float* tp = tg + (size_t)(b * NT + lane) * 5;
        float x0 = tp[0], y0 = tp[1], x1 = tp[2], y1 = tp[3];
        cls = (int)tp[4];
        gx = x0 * gf; gy = y0 * gf;
        gw = fabsf(x1 - x0) * (416.0f * gf);
        gh = fabsf(y1 - y0) * (416.0f * gf);
        int best = 0; float bi = -1.0f;
        { float in0 = fminf(aw0, gw) * fminf(ah0, gh); float u = 1e-8f + aw0 * ah0 + gw * gh - in0; float io = in0 / u; if (io > bi) { bi = io; best = 0; } }
        { float in1 = fminf(aw1, gw) * fminf(ah1, gh); float u = 1e-8f + aw1 * ah1 + gw * gh - in1; float io = in1 / u; if (io > bi) { bi = io; best = 1; } }
        { float in2 = fminf(aw2, gw) * fminf(ah2, gh); float u = 1e-8f + aw2 * ah2 + gw * gh - in2; float io = in2 / u; if (io > bi) { bi = io; best = 2; } }
        key = ((b * NA + best) * g + (int)gx) * g + (int)gy;
    }

    // ---- dedup: last target with same key wins; class union over all matches ----
    const int key_t = __shfl(key, t);
    const unsigned long long m = __ballot(lane < NT && key == key_t);
    const bool win = (m >> (t + 1)) == 0ull;                    // no later target hits this cell
    const unsigned long long mle = m & ((2ull << t) - 1ull);    // matches with index <= t

    unsigned long long lo = 0ull, hi = 0ull;
    if ((mle >> lane) & 1ull) {
        if (cls < 64) lo = 1ull << cls; else hi = 1ull << (cls - 64);
    }
    for (int off = 1; off < 64; off <<= 1) {
        lo |= __shfl_xor(lo, off);
        hi |= __shfl_xor(hi, off);
    }

    // ---- regression targets for slot t (broadcast from lane t) ----
    const float gxt = __shfl(gx, t), gyt = __shfl(gy, t);
    const float gwt = __shfl(gw, t), ght = __shfl(gh, t);
    const int bestt = (key_t / (g * g)) % NA;
    const float awb = (bestt == 0) ? aw0 : (bestt == 1) ? aw1 : aw2;
    const float ahb = (bestt == 0) ? ah0 : (bestt == 1) ? ah1 : ah2;
    const float txv = gxt - floorf(gxt);
    const float tyv = gyt - floorf(gyt);
    const float twv = logf(gwt / awb);
    const float thv = logf(ght / ahb);

    // ---- gather the 85-float cell, accumulate loss terms ----
    double vsq = 0.0, vbce = 0.0;
    if (win) {
        const float* op = (s == 0) ? o0 : (s == 1) ? o1 : o2;
        const float* cell = op + (size_t)key_t * (5 + NCLS);
        {
            float x = cell[lane];                                // elements 0..63
            if (lane < 4) {
                float tv = (lane == 0) ? txv : (lane == 1) ? tyv : (lane == 2) ? twv : thv;
                float d = x - tv;
                vsq = (double)d * d;
            } else if (lane >= 5) {
                int c = lane - 5;                                // classes 0..58
                bool one = (lo >> c) & 1ull;
                float p = fminf(fmaxf(x, 1e-7f), 1.0f - 1e-7f);
                vbce = (double)(one ? -logf(p) : -logf(1.0f - p));
            }
        }
        if (lane < 21) {
            float x = cell[64 + lane];                           // classes 59..79
            int c = 59 + lane;
            bool one = (c < 64) ? ((lo >> c) & 1ull) : ((hi >> (c - 64)) & 1ull);
            float p = fminf(fmaxf(x, 1e-7f), 1.0f - 1e-7f);
            vbce += (double)(one ? -logf(p) : -logf(1.0f - p));
        }
    }
    for (int off = 32; off > 0; off >>= 1) {
        vsq  += __shfl_down(vsq, off);
        vbce += __shfl_down(vbce, off);
    }

    // ---- block partial: 16 waves -> LDS -> one plain store, no atomics ----
    __shared__ double ssq[16], sbce[16];
    __shared__ int    scnt[16];
    if (lane == 0) { ssq[wid] = vsq; sbce[wid] = vbce; scnt[wid] = win ? 1 : 0; }
    __syncthreads();
    if (threadIdx.x == 0) {
        double psq = 0.0, pbce = 0.0; int pcnt = 0;
        for (int w = 0; w < 16; ++w) { psq += ssq[w]; pbce += sbce[w]; pcnt += scnt[w]; }
        BP p; p.sq = psq; p.bce = pbce; p.cnt = (double)pcnt; p.pad = 0.0;
        parts[blockIdx.x] = p;
    }
}

// Final: one small block reduces 180 partials (kernel boundary = coherence).
__global__ __launch_bounds__(256) void yolo_final(
    const BP* __restrict__ parts, float* __restrict__ dout)
{
    const int tid = threadIdx.x;
    const int wid = tid >> 6, lane = tid & 63;

    double vs[3] = {0, 0, 0}, vb[3] = {0, 0, 0}, vc[3] = {0, 0, 0};
    if (tid < NBLK) {                        // one partial per thread, one load round
        BP p = parts[tid];
        int sc = tid / (NBLK / 3);           // scale-pure: 60 blocks per scale
        vs[sc] = p.sq; vb[sc] = p.bce; vc[sc] = p.cnt;
    }
    for (int off = 32; off > 0; off >>= 1)
        for (int sc = 0; sc < 3; ++sc) {
            vs[sc] += __shfl_down(vs[sc], off);
            vb[sc] += __shfl_down(vb[sc], off);
            vc[sc] += __shfl_down(vc[sc], off);
        }
    __shared__ double rs[4][3], rb[4][3], rc[4][3];
    if (lane == 0)
        for (int sc = 0; sc < 3; ++sc) { rs[wid][sc] = vs[sc]; rb[wid][sc] = vb[sc]; rc[wid][sc] = vc[sc]; }
    __syncthreads();
    if (tid == 0) {
        double loss = 0.0;
        for (int sc = 0; sc < 3; ++sc) {
            double sq = 0.0, bce = 0.0, cn = 0.0;
            for (int w = 0; w < 4; ++w) { sq += rs[w][sc]; bce += rb[w][sc]; cn += rc[w][sc]; }
            double c = (cn > 0.0) ? cn : 1.0;
            loss += sq / c + bce / (c * (double)NCLS);
        }
        dout[0] = (float)loss;
    }
}

extern "C" void kernel_launch(void* const* d_in, const int* in_sizes, int n_in,
                              void* d_out, int out_size, void* d_ws, size_t ws_size,
                              hipStream_t stream) {
    const float* o0 = (const float*)d_in[0];
    const float* o1 = (const float*)d_in[1];
    const float* o2 = (const float*)d_in[2];
    const float* a0 = (const float*)d_in[3];
    const float* a1 = (const float*)d_in[4];
    const float* a2 = (const float*)d_in[5];
    const float* tg = (const float*)d_in[6];
    float* out = (float*)d_out;

    BP* parts = (BP*)d_ws;      // 180 * 32 B = 5,760 B

    hipLaunchKernelGGL(yolo_fused, dim3(NBLK), dim3(1024), 0, stream,
                       o0, o1, o2, a0, a1, a2, tg, parts);
    hipLaunchKernelGGL(yolo_final, dim3(1), dim3(256), 0, stream, parts, out);
}